// Round 12
// baseline (238.363 us; speedup 1.0000x reference)
//
#include <hip/hip_runtime.h>

// ---------------------------------------------------------------------------
// AsymAttention on MI355X (gfx950).
// B=16, N=256, M=16, D=768, H=12, Dh=64.  scale = 1/8.
//
// Algebraic refactors:
//  (1) avoid sim k/v projections (155 GF):
//      logits_sim[b,h,n,m] = (se[b,n,m,:].T_row + q_h.bk_h) * scale,
//          T[b,n,h,D] = sum_dh q[b,h,n,dh] * Wk[D, h*64+dh]       (K=64 GEMM)
//      out_sim = Wv_h^T s_v + (sum a_sim) bv,  s_v = sum_m a_sim[m] se[b,n,m,:]
//  (2) single COALESCED se pass in fused_sim (dual-layout bf16 LDS staging).
//  (3) T stored FRAGMENT-PACKED (T'[r][D/32][((D%32)/8)][h][D%8]) so the
//      fused_sim L-GEMM B-frag load is coalesced (4x192B segments/wave) —
//      the row-major layout was a 16-row x 64B HBM gather.
//  (4) launch-graph compression: 6 kernels; qkv 512-thread 256x128 tile.
// ---------------------------------------------------------------------------

typedef __attribute__((ext_vector_type(8))) short short8;   // 8 x bf16 (MFMA frag)
typedef __attribute__((ext_vector_type(4))) float f32x4;    // MFMA acc
typedef __attribute__((ext_vector_type(4))) unsigned short u16x4;

__device__ __forceinline__ float bf2f(unsigned short u) {
  union { unsigned int i; float f; } c; c.i = ((unsigned int)u) << 16; return c.f;
}
__device__ __forceinline__ unsigned short f2bf(float f) {
  union { float f; unsigned int i; } c; c.f = f;
  unsigned int r = c.i + 0x7fffu + ((c.i >> 16) & 1u);   // RNE
  return (unsigned short)(r >> 16);
}

// ------------------------------ prep (1 launch) ----------------------------

__global__ void prep_all(const float* __restrict__ x, unsigned short* __restrict__ x_bf,
                         const float* __restrict__ Wq, const float* __restrict__ Wk,
                         const float* __restrict__ Wv, const float* __restrict__ Wp,
                         unsigned short* __restrict__ Wqkv_t, unsigned short* __restrict__ Wp_t,
                         unsigned short* __restrict__ Wk_bf,
                         const float* __restrict__ bq, const float* __restrict__ bk,
                         const float* __restrict__ bv, float* __restrict__ bqkv) {
  const int bid = blockIdx.x;
  const int tid = threadIdx.x;
  if (bid < 3072) {
    int t = bid * 256 + tid;
    {
      int i = t * 4;
      float4 v = *(const float4*)&x[i];
      x_bf[i+0] = f2bf(v.x); x_bf[i+1] = f2bf(v.y); x_bf[i+2] = f2bf(v.z); x_bf[i+3] = f2bf(v.w);
    }
    if (t < 147456) {
      int i = t * 4;
      float4 v = *(const float4*)&Wk[i];
      Wk_bf[i+0] = f2bf(v.x); Wk_bf[i+1] = f2bf(v.y); Wk_bf[i+2] = f2bf(v.z); Wk_bf[i+3] = f2bf(v.w);
    }
    if (t < 2304) bqkv[t] = (t < 768) ? bq[t] : ((t < 1536) ? bk[t - 768] : bv[t - 1536]);
  } else {
    const int t = bid - 3072;
    const int z = t / 576, xx = t % 576;
    const float* W = (z == 0) ? Wq : (z == 1) ? Wk : (z == 2) ? Wv : Wp;
    unsigned short* Wt = (z == 3) ? Wp_t : (Wqkv_t + (size_t)z * 589824);
    __shared__ float tile[32][33];
    int bx = xx % 24, by = xx / 24;
    int n0 = bx * 32, k0 = by * 32;
    for (int l = tid; l < 1024; l += 256) {
      int i = l >> 5, j = l & 31;
      tile[i][j] = W[(size_t)(k0 + i) * 768 + n0 + j];
    }
    __syncthreads();
    for (int l = tid; l < 1024; l += 256) {
      int i = l >> 5, j = l & 31;
      Wt[(size_t)(n0 + i) * 768 + k0 + j] = f2bf(tile[j][i]);
    }
  }
}

// --------------------- qkv GEMM: 512 threads, 256x128 tile -----------------

__global__ __launch_bounds__(512)
void gemm_qkv(const unsigned short* __restrict__ A,
              const unsigned short* __restrict__ Bt,
              unsigned short* __restrict__ C,
              const float* __restrict__ bias)
{
  int s = blockIdx.x;
  s = (s & 7) * 36 + (s >> 3);              // 288 = 8 * 36, bijective
  const int xb = s % 16, yb = s / 16;       // 16 x 18
  const int row0 = xb * 256;
  const int col0 = yb * 128;
  __shared__ __align__(16) unsigned short lgA[256 * 64];   // 32 KB
  __shared__ __align__(16) unsigned short lgB[128 * 64];   // 16 KB
  const int tid = threadIdx.x;
  const int lane = tid & 63;
  const int w = tid >> 6;                   // 0..7
  const int wr = w >> 1, wc = w & 1;        // 4 x 2
  const int lr = lane & 15, kg = lane >> 4;

  f32x4 acc[4][4];
  #pragma unroll
  for (int m = 0; m < 4; m++)
    #pragma unroll
    for (int n = 0; n < 4; n++)
      #pragma unroll
      for (int q = 0; q < 4; q++) acc[m][n][q] = 0.f;

  for (int k0 = 0; k0 < 768; k0 += 64) {
    __syncthreads();
    #pragma unroll
    for (int it = 0; it < 4; ++it) {        // A: 32 KB, panel 16 KB (256x32)
      const int off = it * 8192 + tid * 16;
      const int kp = off >> 14, row = (off & 16383) >> 6, colb = off & 63;
      const char* ga = (const char*)A + (size_t)(row0 + row) * 1536 + (k0 + kp * 32) * 2 + colb;
      __builtin_amdgcn_global_load_lds((const __attribute__((address_space(1))) unsigned int*)ga,
                                       (__attribute__((address_space(3))) unsigned int*)((char*)lgA + off), 16, 0, 0);
    }
    #pragma unroll
    for (int it = 0; it < 2; ++it) {        // B: 16 KB, panel 8 KB (128x32)
      const int off = it * 8192 + tid * 16;
      const int kp = off >> 13, row = (off & 8191) >> 6, colb = off & 63;
      const char* gb = (const char*)Bt + (size_t)(col0 + row) * 1536 + (k0 + kp * 32) * 2 + colb;
      __builtin_amdgcn_global_load_lds((const __attribute__((address_space(1))) unsigned int*)gb,
                                       (__attribute__((address_space(3))) unsigned int*)((char*)lgB + off), 16, 0, 0);
    }
    __syncthreads();
    #pragma unroll
    for (int kk = 0; kk < 64; kk += 32) {
      short8 af[4], bfr[4];
      #pragma unroll
      for (int m = 0; m < 4; m++)
        af[m] = *(const short8*)&lgA[(kk >> 5) * (256 * 32) + (wr * 64 + m * 16 + lr) * 32 + kg * 8];
      #pragma unroll
      for (int n = 0; n < 4; n++)
        bfr[n] = *(const short8*)&lgB[(kk >> 5) * (128 * 32) + (wc * 64 + n * 16 + lr) * 32 + kg * 8];
      #pragma unroll
      for (int m = 0; m < 4; m++)
        #pragma unroll
        for (int n = 0; n < 4; n++)
          acc[m][n] = __builtin_amdgcn_mfma_f32_16x16x32_bf16(af[m], bfr[n], acc[m][n], 0, 0, 0);
    }
  }

  #pragma unroll
  for (int m = 0; m < 4; m++)
    #pragma unroll
    for (int n = 0; n < 4; n++) {
      const int gc = col0 + wc * 64 + n * 16 + lr;
      #pragma unroll
      for (int j = 0; j < 4; j++) {
        const int gr = row0 + wr * 64 + m * 16 + kg * 4 + j;
        C[(size_t)gr * 2304 + gc] = f2bf(acc[m][n][j] + bias[gc]);
      }
    }
}

// ------------------------------- GEMM (generic) ----------------------------
// ZY=true : z  = s/NXB (yb=0)   — per-head GEMMs (outsim)
// ZY=false: yb = s/NXB, z=bIdx.z — plain column tiling (final)

template<bool OUT_BF16, bool SELFC, int BN, int NXB, bool SWZ, bool ZY>
__global__ __launch_bounds__(256)
void gemm_bt(const unsigned short* __restrict__ A, int lda, int zsA,
             const unsigned short* __restrict__ Bt, int ldb, int zsB,
             void* __restrict__ Cv, int ldc, int zsC,
             int M, int Nvalid, int K, int nblk,
             const float* __restrict__ bias,
             const float* __restrict__ selfacc,
             const float* __restrict__ scl,
             const float* __restrict__ simw,
             const float* __restrict__ bv2)
{
  constexpr int TBK = 64;
  constexpr int NF  = BN / 32;
  constexpr int AIT = (128 * TBK * 2) / 4096;
  constexpr int BIT = (BN  * TBK * 2) / 4096;
  constexpr int PA  = 128 * 64;
  constexpr int PB  = BN * 64;
  int s = blockIdx.x;
  if (SWZ) { const int cpx = nblk >> 3; s = (s & 7) * cpx + (s >> 3); }
  const int xb = s % NXB;
  const int sq = s / NXB;
  const int yb = ZY ? 0 : sq;
  const int z  = ZY ? sq : blockIdx.z;
  A  += (size_t)zsA * z;
  Bt += (size_t)zsB * z;
  const int row0 = xb * 128;
  const int col0 = yb * BN;
  __shared__ __align__(16) unsigned short lgA[128 * TBK];
  __shared__ __align__(16) unsigned short lgB[BN * TBK];
  const int tid = threadIdx.x;
  const int lane = tid & 63;
  const int w = tid >> 6;
  const int wr = w >> 1, wc = w & 1;
  const int lr = lane & 15, kg = lane >> 4;

  f32x4 acc[4][NF];
  #pragma unroll
  for (int m = 0; m < 4; m++)
    #pragma unroll
    for (int n = 0; n < NF; n++)
      #pragma unroll
      for (int q = 0; q < 4; q++) acc[m][n][q] = 0.f;

  for (int k0 = 0; k0 < K; k0 += TBK) {
    __syncthreads();
    #pragma unroll
    for (int it = 0; it < AIT; ++it) {
      const int off = it * 4096 + tid * 16;
      const int kp = off / PA, row = (off % PA) >> 6, colb = off & 63;
      const char* ga = (const char*)A + (size_t)(row0 + row) * (lda * 2) + (k0 + kp * 32) * 2 + colb;
      __builtin_amdgcn_global_load_lds((const __attribute__((address_space(1))) unsigned int*)ga,
                                       (__attribute__((address_space(3))) unsigned int*)((char*)lgA + off), 16, 0, 0);
    }
    #pragma unroll
    for (int it = 0; it < BIT; ++it) {
      const int off = it * 4096 + tid * 16;
      const int kp = off / PB, row = (off % PB) >> 6, colb = off & 63;
      const char* gb = (const char*)Bt + (size_t)(col0 + row) * (ldb * 2) + (k0 + kp * 32) * 2 + colb;
      __builtin_amdgcn_global_load_lds((const __attribute__((address_space(1))) unsigned int*)gb,
                                       (__attribute__((address_space(3))) unsigned int*)((char*)lgB + off), 16, 0, 0);
    }
    __syncthreads();
    #pragma unroll
    for (int kk = 0; kk < TBK; kk += 32) {
      short8 af[4], bfr[NF];
      #pragma unroll
      for (int m = 0; m < 4; m++)
        af[m] = *(const short8*)&lgA[(kk >> 5) * (128 * 32) + (wr * 64 + m * 16 + lr) * 32 + kg * 8];
      #pragma unroll
      for (int n = 0; n < NF; n++)
        bfr[n] = *(const short8*)&lgB[(kk >> 5) * (BN * 32) + (wc * (BN / 2) + n * 16 + lr) * 32 + kg * 8];
      #pragma unroll
      for (int m = 0; m < 4; m++)
        #pragma unroll
        for (int n = 0; n < NF; n++)
          acc[m][n] = __builtin_amdgcn_mfma_f32_16x16x32_bf16(af[m], bfr[n], acc[m][n], 0, 0, 0);
    }
  }

  #pragma unroll
  for (int m = 0; m < 4; m++) {
    #pragma unroll
    for (int n = 0; n < NF; n++) {
      const int gc = col0 + wc * (BN / 2) + n * 16 + lr;
      if (gc >= Nvalid) continue;
      #pragma unroll
      for (int j = 0; j < 4; j++) {
        const int gr = row0 + wr * 64 + m * 16 + kg * 4 + j;
        if (gr >= M) continue;
        float v = acc[m][n][j];
        if (bias) v += bias[gc];
        if (SELFC) {
          v += selfacc[(size_t)gr * 768 + z * 64 + gc] * scl[(size_t)gr * 12 + z]
             + simw[(size_t)gr * 12 + z] * bv2[z * 64 + gc];
        }
        const size_t idx = (size_t)gr * ldc + gc;
        if (OUT_BF16) {
          unsigned short* C = (unsigned short*)Cv + (size_t)zsC * z;
          C[idx] = f2bf(v);
        } else {
          float* C = (float*)Cv + (size_t)zsC * z;
          C[idx] = v;
        }
      }
    }
  }
}

// ----------------- merged: attn_self (768 blks) + T-GEMM (2304) ------------
// T is written FRAGMENT-PACKED:
//   T'[r*9216 + (D>>5)*384 + ((D&31)>>3)*96 + h*8 + (D&7)]  (u16 units)
// so fused_sim's B-frag load is coalesced.  Same 9216 u16/row footprint.

__global__ __launch_bounds__(256, 2)
void tattn_kernel(const unsigned short* __restrict__ qkv,
                  const unsigned short* __restrict__ Wk_bf,
                  unsigned short* __restrict__ Tbuf,
                  float* __restrict__ selfacc,
                  float* __restrict__ mstat,
                  float* __restrict__ sstat)
{
  __shared__ __align__(16) char smem[70656];
  const int tid = threadIdx.x;
  const int lane = tid & 63;
  const int w = tid >> 6;
  const int lr = lane & 15, kg = lane >> 4;

  if (blockIdx.x >= 768) {
    // ---------------- T-GEMM body ----------------
    const int bid = blockIdx.x - 768;
    const int xb = bid % 32, yb = (bid / 32) % 6, z = bid / 192;
    const int row0 = xb * 128, col0 = yb * 128;
    const int wr = w >> 1, wc = w & 1;
    const unsigned short* A  = qkv + 64 * z;          // lda 2304
    const unsigned short* Bt = Wk_bf + 64 * z;        // ldb 768
    unsigned short* lgA = (unsigned short*)smem;               // 128x64
    unsigned short* lgB = (unsigned short*)(smem + 16384);     // 128x64

    f32x4 acc[4][4];
    #pragma unroll
    for (int m = 0; m < 4; m++)
      #pragma unroll
      for (int n = 0; n < 4; n++)
        #pragma unroll
        for (int q = 0; q < 4; q++) acc[m][n][q] = 0.f;

    #pragma unroll
    for (int it = 0; it < 4; ++it) {
      const int off = it * 4096 + tid * 16;
      const int kp = off / 8192, row = (off % 8192) >> 6, colb = off & 63;
      const char* ga = (const char*)A + (size_t)(row0 + row) * 4608 + (kp * 32) * 2 + colb;
      __builtin_amdgcn_global_load_lds((const __attribute__((address_space(1))) unsigned int*)ga,
                                       (__attribute__((address_space(3))) unsigned int*)((char*)lgA + off), 16, 0, 0);
      const char* gb = (const char*)Bt + (size_t)(col0 + row) * 1536 + (kp * 32) * 2 + colb;
      __builtin_amdgcn_global_load_lds((const __attribute__((address_space(1))) unsigned int*)gb,
                                       (__attribute__((address_space(3))) unsigned int*)((char*)lgB + off), 16, 0, 0);
    }
    __syncthreads();
    #pragma unroll
    for (int kk = 0; kk < 64; kk += 32) {
      short8 af[4], bfr[4];
      #pragma unroll
      for (int m = 0; m < 4; m++)
        af[m] = *(const short8*)&lgA[(kk >> 5) * 4096 + (wr * 64 + m * 16 + lr) * 32 + kg * 8];
      #pragma unroll
      for (int n = 0; n < 4; n++)
        bfr[n] = *(const short8*)&lgB[(kk >> 5) * 4096 + (wc * 64 + n * 16 + lr) * 32 + kg * 8];
      #pragma unroll
      for (int m = 0; m < 4; m++)
        #pragma unroll
        for (int n = 0; n < 4; n++)
          acc[m][n] = __builtin_amdgcn_mfma_f32_16x16x32_bf16(af[m], bfr[n], acc[m][n], 0, 0, 0);
    }
    #pragma unroll
    for (int m = 0; m < 4; m++)
      #pragma unroll
      for (int n = 0; n < 4; n++) {
        const int gc = col0 + wc * 64 + n * 16 + lr;           // D
        const int fbase = ((gc >> 5) * 384) + (((gc & 31) >> 3) * 96) + z * 8 + (gc & 7);
        #pragma unroll
        for (int j = 0; j < 4; j++) {
          const int gr = row0 + wr * 64 + m * 16 + kg * 4 + j; // r
          Tbuf[(size_t)gr * 9216 + fbase] = f2bf(acc[m][n][j]);
        }
      }
    return;
  }

  // ---------------- attn_self body ----------------
  const int bh = blockIdx.x >> 2;
  const int qq = blockIdx.x & 3;
  const int b = bh / 12;
  const int h = bh % 12;
  const size_t rowbase = (size_t)b * 256;
  const int rows0 = qq * 64 + w * 16;            // this wave's 16 q-rows

  unsigned short* Ks = (unsigned short*)smem;             // [256][72]
  unsigned short* VT = (unsigned short*)(smem + 36864);   // [64][264]  VT[d][k]=V[k][d]
  unsigned short* aL = (unsigned short*)(smem + (size_t)w * 4352); // [16][136]/wave, aliases Ks

  for (int it = 0; it < 8; ++it) {
    const int idx = tid * 8 + it * 2048;
    const int row = idx >> 6, d = idx & 63;
    *(short8*)&Ks[row * 72 + d] =
        *(const short8*)&qkv[(rowbase + row) * 2304 + 768 + h * 64 + d];
  }
  #pragma unroll
  for (int it = 0; it < 16; ++it) {
    const int kk = w * 64 + it * 4 + kg;
    const int d0 = lr * 4;
    u16x4 v4 = *(const u16x4*)&qkv[(rowbase + kk) * 2304 + 1536 + h * 64 + d0];
    VT[(d0+0) * 264 + kk] = v4.x;
    VT[(d0+1) * 264 + kk] = v4.y;
    VT[(d0+2) * 264 + kk] = v4.z;
    VT[(d0+3) * 264 + kk] = v4.w;
  }
  __syncthreads();

  f32x4 acc[16];
  #pragma unroll
  for (int n = 0; n < 16; n++)
    #pragma unroll
    for (int q = 0; q < 4; q++) acc[n][q] = 0.f;

  #pragma unroll
  for (int ks = 0; ks < 64; ks += 32) {           // QK^T, K=64; Q from global
    short8 af = *(const short8*)&qkv[(rowbase + rows0 + lr) * 2304 + h * 64 + ks + kg * 8];
    #pragma unroll
    for (int n = 0; n < 16; n++) {
      short8 bfr = *(const short8*)&Ks[(n * 16 + lr) * 72 + ks + kg * 8];
      acc[n] = __builtin_amdgcn_mfma_f32_16x16x32_bf16(af, bfr, acc[n], 0, 0, 0);
    }
  }

  #pragma unroll
  for (int j = 0; j < 4; j++) {
    float vmx = -1e30f;
    #pragma unroll
    for (int n = 0; n < 16; n++) { float s = acc[n][j] * 0.125f; acc[n][j] = s; vmx = fmaxf(vmx, s); }
    #pragma unroll
    for (int s = 1; s < 16; s <<= 1) vmx = fmaxf(vmx, __shfl_xor(vmx, s));
    float sum = 0.f;
    #pragma unroll
    for (int n = 0; n < 16; n++) { float e = __expf(acc[n][j] - vmx); acc[n][j] = e; sum += e; }
    #pragma unroll
    for (int s = 1; s < 16; s <<= 1) sum += __shfl_xor(sum, s);
    if (lr == 0) {
      const int row = rows0 + kg * 4 + j;
      mstat[(rowbase + row) * 12 + h] = vmx;
      sstat[(rowbase + row) * 12 + h] = sum;
    }
  }

  __syncthreads();   // all waves done reading Ks before aL overwrites it

  f32x4 acc2[4];
  #pragma unroll
  for (int m = 0; m < 4; m++)
    #pragma unroll
    for (int q = 0; q < 4; q++) acc2[m][q] = 0.f;

  #pragma unroll
  for (int hl = 0; hl < 2; ++hl) {   // PV in two 128-col halves
    #pragma unroll
    for (int j = 0; j < 4; j++) {
      const int rw = kg * 4 + j;
      #pragma unroll
      for (int n2 = 0; n2 < 8; n2++)
        aL[rw * 136 + n2 * 16 + lr] = f2bf(acc[hl * 8 + n2][j]);   // unnormalized
    }
    #pragma unroll
    for (int ks2 = 0; ks2 < 4; ++ks2) {   // out^T = VT * a^T
      short8 pf = *(const short8*)&aL[lr * 136 + ks2 * 32 + kg * 8];
      #pragma unroll
      for (int mm = 0; mm < 4; mm++) {
        short8 vf = *(const short8*)&VT[(mm * 16 + lr) * 264 + hl * 128 + ks2 * 32 + kg * 8];
        acc2[mm] = __builtin_amdgcn_mfma_f32_16x16x32_bf16(vf, pf, acc2[mm], 0, 0, 0);
      }
    }
  }

  #pragma unroll
  for (int mm = 0; mm < 4; mm++)      // D rows = dh, D cols = q-row (lr)
    #pragma unroll
    for (int j = 0; j < 4; j++) {
      const int dh = mm * 16 + kg * 4 + j;
      const int rn = rows0 + lr;
      selfacc[(rowbase + rn) * 768 + h * 64 + dh] = acc2[mm][j];   // f32 unnorm
    }
}

// --------------------- fused sim logits + renorm + s_v (MFMA) --------------
// One block per (b,n) = r, 8 waves, 512 threads.  T read fragment-packed.

__global__ __launch_bounds__(512, 4)
void fused_sim_kernel(const float* __restrict__ se, const unsigned short* __restrict__ T,
                      const unsigned short* __restrict__ qkv, const float* __restrict__ bk,
                      const float* __restrict__ mstat, const float* __restrict__ sstat,
                      unsigned short* __restrict__ s_v,
                      float* __restrict__ sclA, float* __restrict__ simwA)
{
  const int r = blockIdx.x;                    // b*256+n
  __shared__ __align__(16) unsigned int SE_T32[768 * 9];   // 27648 B
  __shared__ __align__(16) unsigned int SErm[16][388];     // 24832 B (776-elem rows)
  __shared__ __align__(16) float Lp[8][64][4];             // 8192 B
  __shared__ float qb[16];
  const int tid = threadIdx.x;
  const int w = tid >> 6, lane = tid & 63;
  const int lr = lane & 15, kg = lane >> 4;

  // ---- coalesced stage: wave w owns se rows m = {2w, 2w+1} ----
  const float* se_r = se + (size_t)r * 12288;
  unsigned short va[2][12];
  #pragma unroll
  for (int c = 0; c < 3; ++c) {
    float4 fa = *(const float4*)&se_r[(2 * w) * 768 + c * 256 + lane * 4];
    float4 fb = *(const float4*)&se_r[(2 * w + 1) * 768 + c * 256 + lane * 4];
    va[0][c*4+0] = f2bf(fa.x); va[0][c*4+1] = f2bf(fa.y); va[0][c*4+2] = f2bf(fa.z); va[0][c*4+3] = f2bf(fa.w);
    va[1][c*4+0] = f2bf(fb.x); va[1][c*4+1] = f2bf(fb.y); va[1][c*4+2] = f2bf(fb.z); va[1][c*4+3] = f2bf(fb.w);
  }
  #pragma unroll
  for (int c = 0; c < 3; ++c) {
    #pragma unroll
    for (int j = 0; j < 4; ++j) {        // SE_T: m-pair packed, swizzled dword col
      const int d = c * 256 + lane * 4 + j;
      SE_T32[d * 9 + (w ^ ((d >> 5) & 7))] =
          (unsigned int)va[0][c*4+j] | ((unsigned int)va[1][c*4+j] << 16);
    }
    #pragma unroll
    for (int rr = 0; rr < 2; ++rr) {     // SErm: row-major k-pairs, b64 writes
      uint2 pk;
      pk.x = (unsigned int)va[rr][c*4+0] | ((unsigned int)va[rr][c*4+1] << 16);
      pk.y = (unsigned int)va[rr][c*4+2] | ((unsigned int)va[rr][c*4+3] << 16);
      *(uint2*)&SErm[2 * w + rr][c * 128 + lane * 2] = pk;
    }
  }
  // qb[h] = q_h . bk_h  (waves 0..5, 2 heads each)
  if (w < 6) {
    #pragma unroll
    for (int i = 0; i < 2; ++i) {
      const int hh = w * 2 + i;
      float p = bf2f(qkv[(size_t)r * 2304 + hh * 64 + lane]) * bk[hh * 64 + lane];
      #pragma unroll
      for (int sft = 32; sft; sft >>= 1) p += __shfl_xor(p, sft);
      if (lane == 0) qb[hh] = p;
    }
  }
  if (tid < 4) qb[12 + tid] = 0.f;

  // T B-frags, fragment-packed: chunk c=w*3+s, lane (lr,kg) -> contiguous
  const int hsel = (lr < 12) ? lr : 11;   // lanes 12-15 duplicate h=11 (discarded)
  short8 bfr[3];
  #pragma unroll
  for (int s = 0; s < 3; ++s) {
    const int c = w * 3 + s;
    bfr[s] = *(const short8*)&T[(size_t)r * 9216 + c * 384 + kg * 96 + hsel * 8];
  }

  __syncthreads();

  // ---- L-GEMM partial: K in [w*96, w*96+96) ----
  f32x4 accL = {0.f, 0.f, 0.f, 0.f};
  #pragma unroll
  for (int s = 0; s < 3; ++s) {
    const int kb = w * 96 + s * 32 + kg * 8;
    short8 af = *(const short8*)&SErm[lr][kb >> 1];
    accL = __builtin_amdgcn_mfma_f32_16x16x32_bf16(af, bfr[s], accL, 0, 0, 0);
  }
  *(f32x4*)&Lp[w][lane][0] = accL;
  __syncthreads();

  // ---- softmax + joint renorm (redundant per wave; m=kg*4+j, h=lr) ----
  float vals[4] = {0.f, 0.f, 0.f, 0.f};
  #pragma unroll
  for (int ww = 0; ww < 8; ++ww) {
    f32x4 p = *(const f32x4*)&Lp[ww][lane][0];
    vals[0] += p[0]; vals[1] += p[1]; vals[2] += p[2]; vals[3] += p[3];
  }
  #pragma unroll
  for (int j = 0; j < 4; ++j) vals[j] = vals[j] * 0.125f + qb[lr];
  float mx = fmaxf(fmaxf(vals[0], vals[1]), fmaxf(vals[2], vals[3]));
  mx = fmaxf(mx, __shfl_xor(mx, 16));
  mx = fmaxf(mx, __shfl_xor(mx, 32));
  const int hidx = r * 12 + (lr < 12 ? lr : 11);
  const float msf = mstat[hidx];
  const float ssf = sstat[hidx];
  const float mj = fmaxf(mx, msf);
  float ea[4];
  #pragma unroll
  for (int j = 0; j < 4; ++j) ea[j] = __expf(vals[j] - mj);
  float ssum = ea[0] + ea[1] + ea[2] + ea[3];
  ssum += __shfl_xor(ssum, 16);
  ssum += __shfl_xor(ssum, 32);
  const float alpha = __expf(msf - mj);
  const float invZ = 1.0f / (ssf * alpha + ssum);
  float a[4];
  #pragma unroll
  for (int j = 0; j < 4; ++j) a[j] = ea[j] * invZ;
  if (w == 0 && kg == 0 && lr < 12) {
    sclA[(size_t)r * 12 + lr]  = alpha * invZ;
    simwA[(size_t)r * 12 + lr] = ssum * invZ;
  }

  // ---- a^T A-frag: lane (h=lr, kg) needs a[m=kg*8+e][h], zeros for kg>=2 ----
  short8 af8;
  #pragma unroll
  for (int e = 0; e < 8; ++e) {
    const int src = lr + ((kg & 1) * 2 + (e >> 2)) * 16;
    const float v = __shfl(a[e & 3], src);
    af8[e] = (kg < 2) ? (short)f2bf(v) : (short)0;
  }

  // ---- s_v GEMM: 6 d-tiles per wave, one mfma each ----
  #pragma unroll
  for (int i = 0; i < 6; ++i) {
    const int ntile = w + i * 8;
    const int row = ntile * 16 + lr;
    const int sw = (row >> 5) & 7;
    union { unsigned int u[4]; short8 s8; } bu;
    #pragma unroll
    for (int j = 0; j < 4; ++j)
      bu.u[j] = SE_T32[row * 9 + (((kg & 1) * 4 + j) ^ sw)];
    f32x4 cacc = {0.f, 0.f, 0.f, 0.f};
    cacc = __builtin_amdgcn_mfma_f32_16x16x32_bf16(af8, bu.s8, cacc, 0, 0, 0);
    if (kg < 3) {
      #pragma unroll
      for (int j = 0; j < 4; ++j) {
        const int h = kg * 4 + j;
        s_v[(size_t)r * 9216 + h * 768 + ntile * 16 + lr] = f2bf(cacc[j]);
      }
    }
  }
}

// ------------------------------- launcher ----------------------------------

extern "C" void kernel_launch(void* const* d_in, const int* in_sizes, int n_in,
                              void* d_out, int out_size, void* d_ws, size_t ws_size,
                              hipStream_t stream) {
  const float* x  = (const float*)d_in[0];
  const float* se = (const float*)d_in[1];
  const float* Wq = (const float*)d_in[2];
  const float* bq = (const float*)d_in[3];
  const float* Wk = (const float*)d_in[4];
  const float* bk = (const float*)d_in[5];
  const float* Wv = (const float*)d_in[6];
  const float* bv = (const float*)d_in[7];
  const float* Wp = (const float*)d_in[8];
  const float* bp = (const float*)d_in[9];
  float* out = (float*)d_out;
  char* ws = (char*)d_ws;

  // workspace layout (256B-aligned), total ~120.4 MB
  unsigned short* x_bf    = (unsigned short*)(ws);                 // 4096x768   bf16
  unsigned short* Wqkv_t  = (unsigned short*)(ws + 6291456);       // 2304x768   bf16  Wq^T|Wk^T|Wv^T rows
  unsigned short* Wp_t    = (unsigned short*)(ws + 9830400);       // 768x768    bf16
  unsigned short* Wk_bf   = (unsigned short*)(ws + 11010048);      // 768x768    bf16 (untransposed)
  float*          bqkv    = (float*)(ws + 12189696);               // 2304       f32
  unsigned short* qkv     = (unsigned short*)(ws + 12198912);      // 4096x2304  bf16  q|k|v
  unsigned short* Tbuf    = (unsigned short*)(ws + 31073280);      // 4096x9216  bf16  T' (frag-packed), then s_v
  float*          selfacc = (float*)(ws + 106570752);              // 4096x768   f32  unnorm out_self
  float*          mstat   = (float*)(ws + 119153664);              // 4096x12    f32
  float*          sstat   = (float*)(ws + 119350272);              // 4096x12    f32
  float*          sclA    = (float*)(ws + 119546880);              // 4096x12    f32
  float*          simwA   = (float*)(ws + 119743488);              // 4096x12    f32
  unsigned short* att     = (unsigned short*)(ws + 119940096);     // 4096x768   bf16

  prep_all<<<5376, 256, 0, stream>>>(x, x_bf, Wq, Wk, Wv, Wp, Wqkv_t, Wp_t,
                                     Wk_bf, bq, bk, bv, bqkv);

  // qkv = x @ [Wq|Wk|Wv] + bias: 256x128 tile, 512 threads, 288 blocks
  gemm_qkv<<<288, 512, 0, stream>>>(x_bf, Wqkv_t, qkv, bqkv);

  // merged: attn_self (768 blocks) + T-GEMM (2304 blocks, frag-packed T')
  tattn_kernel<<<3072, 256, 0, stream>>>(qkv, Wk_bf, Tbuf, selfacc, mstat, sstat);

  fused_sim_kernel<<<4096, 512, 0, stream>>>(se, Tbuf, qkv, bk, mstat, sstat,
                                             Tbuf /* s_v overwrites T' in-place per r */,
                                             sclA, simwA);

  // att = selfacc*scl + s_v_h @ Wv_h + simw*bv_h   (ZY: z = s/32, 384 blocks)
  gemm_bt<true, true, 64, 32, true, true><<<384, 256, 0, stream>>>(
      Tbuf, 9216, 768, Wqkv_t + 1536 * 768, 768, 64 * 768, att, 768, 64,
      4096, 64, 768, 384, nullptr, selfacc, sclA, simwA, bv);
  // out = att @ Wp + bp  (f32 out), yb = s/32 (ZY=false), 384 blocks, swizzled
  gemm_bt<false, false, 64, 32, true, false><<<384, 256, 0, stream>>>(
      att, 768, 0, Wp_t, 768, 0, out, 768, 0, 4096, 768, 768, 384,
      bp, nullptr, nullptr, nullptr, nullptr);
}

// Round 13
// 197.548 us; speedup vs baseline: 1.2066x; 1.2066x over previous
//
#include <hip/hip_runtime.h>

// ---------------------------------------------------------------------------
// AsymAttention on MI355X (gfx950).
// B=16, N=256, M=16, D=768, H=12, Dh=64.  scale = 1/8.
//
// Algebraic refactors:
//  (1) avoid sim k/v projections (155 GF):
//      logits_sim[b,h,n,m] = (se[b,n,m,:].T_row + q_h.bk_h) * scale,
//          T[b,n,h,D] = sum_dh q[b,h,n,dh] * Wk[D, h*64+dh]       (K=64 GEMM)
//      out_sim = Wv_h^T s_v + (sum a_sim) bv,  s_v = sum_m a_sim[m] se[b,n,m,:]
//  (2) single COALESCED se pass in fused_sim (dual-layout bf16 LDS staging).
//  (3) T row-major [r][h][D] — R12's fragment-packed T' regressed 21%:
//      it made 12 concurrent blocks co-own every T cache line on the WRITE
//      side (partial-line write-allocate + cross-XCD ping-pong).  The R11
//      read-gather is fine: each fused_sim block consumes the whole row, so
//      L2 serves every line fully.
//  (4) launch-graph compression: 6 kernels; qkv 512-thread 256x128 tile.
// ---------------------------------------------------------------------------

typedef __attribute__((ext_vector_type(8))) short short8;   // 8 x bf16 (MFMA frag)
typedef __attribute__((ext_vector_type(4))) float f32x4;    // MFMA acc
typedef __attribute__((ext_vector_type(4))) unsigned short u16x4;

__device__ __forceinline__ float bf2f(unsigned short u) {
  union { unsigned int i; float f; } c; c.i = ((unsigned int)u) << 16; return c.f;
}
__device__ __forceinline__ unsigned short f2bf(float f) {
  union { float f; unsigned int i; } c; c.f = f;
  unsigned int r = c.i + 0x7fffu + ((c.i >> 16) & 1u);   // RNE
  return (unsigned short)(r >> 16);
}

// ------------------------------ prep (1 launch) ----------------------------

__global__ void prep_all(const float* __restrict__ x, unsigned short* __restrict__ x_bf,
                         const float* __restrict__ Wq, const float* __restrict__ Wk,
                         const float* __restrict__ Wv, const float* __restrict__ Wp,
                         unsigned short* __restrict__ Wqkv_t, unsigned short* __restrict__ Wp_t,
                         unsigned short* __restrict__ Wk_bf,
                         const float* __restrict__ bq, const float* __restrict__ bk,
                         const float* __restrict__ bv, float* __restrict__ bqkv) {
  const int bid = blockIdx.x;
  const int tid = threadIdx.x;
  if (bid < 3072) {
    int t = bid * 256 + tid;
    {
      int i = t * 4;
      float4 v = *(const float4*)&x[i];
      x_bf[i+0] = f2bf(v.x); x_bf[i+1] = f2bf(v.y); x_bf[i+2] = f2bf(v.z); x_bf[i+3] = f2bf(v.w);
    }
    if (t < 147456) {
      int i = t * 4;
      float4 v = *(const float4*)&Wk[i];
      Wk_bf[i+0] = f2bf(v.x); Wk_bf[i+1] = f2bf(v.y); Wk_bf[i+2] = f2bf(v.z); Wk_bf[i+3] = f2bf(v.w);
    }
    if (t < 2304) bqkv[t] = (t < 768) ? bq[t] : ((t < 1536) ? bk[t - 768] : bv[t - 1536]);
  } else {
    const int t = bid - 3072;
    const int z = t / 576, xx = t % 576;
    const float* W = (z == 0) ? Wq : (z == 1) ? Wk : (z == 2) ? Wv : Wp;
    unsigned short* Wt = (z == 3) ? Wp_t : (Wqkv_t + (size_t)z * 589824);
    __shared__ float tile[32][33];
    int bx = xx % 24, by = xx / 24;
    int n0 = bx * 32, k0 = by * 32;
    for (int l = tid; l < 1024; l += 256) {
      int i = l >> 5, j = l & 31;
      tile[i][j] = W[(size_t)(k0 + i) * 768 + n0 + j];
    }
    __syncthreads();
    for (int l = tid; l < 1024; l += 256) {
      int i = l >> 5, j = l & 31;
      Wt[(size_t)(n0 + i) * 768 + k0 + j] = f2bf(tile[j][i]);
    }
  }
}

// --------------------- qkv GEMM: 512 threads, 256x128 tile -----------------

__global__ __launch_bounds__(512)
void gemm_qkv(const unsigned short* __restrict__ A,
              const unsigned short* __restrict__ Bt,
              unsigned short* __restrict__ C,
              const float* __restrict__ bias)
{
  int s = blockIdx.x;
  s = (s & 7) * 36 + (s >> 3);              // 288 = 8 * 36, bijective
  const int xb = s % 16, yb = s / 16;       // 16 x 18
  const int row0 = xb * 256;
  const int col0 = yb * 128;
  __shared__ __align__(16) unsigned short lgA[256 * 64];   // 32 KB
  __shared__ __align__(16) unsigned short lgB[128 * 64];   // 16 KB
  const int tid = threadIdx.x;
  const int lane = tid & 63;
  const int w = tid >> 6;                   // 0..7
  const int wr = w >> 1, wc = w & 1;        // 4 x 2
  const int lr = lane & 15, kg = lane >> 4;

  f32x4 acc[4][4];
  #pragma unroll
  for (int m = 0; m < 4; m++)
    #pragma unroll
    for (int n = 0; n < 4; n++)
      #pragma unroll
      for (int q = 0; q < 4; q++) acc[m][n][q] = 0.f;

  for (int k0 = 0; k0 < 768; k0 += 64) {
    __syncthreads();
    #pragma unroll
    for (int it = 0; it < 4; ++it) {        // A: 32 KB, panel 16 KB (256x32)
      const int off = it * 8192 + tid * 16;
      const int kp = off >> 14, row = (off & 16383) >> 6, colb = off & 63;
      const char* ga = (const char*)A + (size_t)(row0 + row) * 1536 + (k0 + kp * 32) * 2 + colb;
      __builtin_amdgcn_global_load_lds((const __attribute__((address_space(1))) unsigned int*)ga,
                                       (__attribute__((address_space(3))) unsigned int*)((char*)lgA + off), 16, 0, 0);
    }
    #pragma unroll
    for (int it = 0; it < 2; ++it) {        // B: 16 KB, panel 8 KB (128x32)
      const int off = it * 8192 + tid * 16;
      const int kp = off >> 13, row = (off & 8191) >> 6, colb = off & 63;
      const char* gb = (const char*)Bt + (size_t)(col0 + row) * 1536 + (k0 + kp * 32) * 2 + colb;
      __builtin_amdgcn_global_load_lds((const __attribute__((address_space(1))) unsigned int*)gb,
                                       (__attribute__((address_space(3))) unsigned int*)((char*)lgB + off), 16, 0, 0);
    }
    __syncthreads();
    #pragma unroll
    for (int kk = 0; kk < 64; kk += 32) {
      short8 af[4], bfr[4];
      #pragma unroll
      for (int m = 0; m < 4; m++)
        af[m] = *(const short8*)&lgA[(kk >> 5) * (256 * 32) + (wr * 64 + m * 16 + lr) * 32 + kg * 8];
      #pragma unroll
      for (int n = 0; n < 4; n++)
        bfr[n] = *(const short8*)&lgB[(kk >> 5) * (128 * 32) + (wc * 64 + n * 16 + lr) * 32 + kg * 8];
      #pragma unroll
      for (int m = 0; m < 4; m++)
        #pragma unroll
        for (int n = 0; n < 4; n++)
          acc[m][n] = __builtin_amdgcn_mfma_f32_16x16x32_bf16(af[m], bfr[n], acc[m][n], 0, 0, 0);
    }
  }

  #pragma unroll
  for (int m = 0; m < 4; m++)
    #pragma unroll
    for (int n = 0; n < 4; n++) {
      const int gc = col0 + wc * 64 + n * 16 + lr;
      #pragma unroll
      for (int j = 0; j < 4; j++) {
        const int gr = row0 + wr * 64 + m * 16 + kg * 4 + j;
        C[(size_t)gr * 2304 + gc] = f2bf(acc[m][n][j] + bias[gc]);
      }
    }
}

// ------------------------------- GEMM (generic) ----------------------------
// ZY=true : z  = s/NXB (yb=0)   — per-head GEMMs (outsim)
// ZY=false: yb = s/NXB, z=bIdx.z — plain column tiling (final)

template<bool OUT_BF16, bool SELFC, int BN, int NXB, bool SWZ, bool ZY>
__global__ __launch_bounds__(256)
void gemm_bt(const unsigned short* __restrict__ A, int lda, int zsA,
             const unsigned short* __restrict__ Bt, int ldb, int zsB,
             void* __restrict__ Cv, int ldc, int zsC,
             int M, int Nvalid, int K, int nblk,
             const float* __restrict__ bias,
             const float* __restrict__ selfacc,
             const float* __restrict__ scl,
             const float* __restrict__ simw,
             const float* __restrict__ bv2)
{
  constexpr int TBK = 64;
  constexpr int NF  = BN / 32;
  constexpr int AIT = (128 * TBK * 2) / 4096;
  constexpr int BIT = (BN  * TBK * 2) / 4096;
  constexpr int PA  = 128 * 64;
  constexpr int PB  = BN * 64;
  int s = blockIdx.x;
  if (SWZ) { const int cpx = nblk >> 3; s = (s & 7) * cpx + (s >> 3); }
  const int xb = s % NXB;
  const int sq = s / NXB;
  const int yb = ZY ? 0 : sq;
  const int z  = ZY ? sq : blockIdx.z;
  A  += (size_t)zsA * z;
  Bt += (size_t)zsB * z;
  const int row0 = xb * 128;
  const int col0 = yb * BN;
  __shared__ __align__(16) unsigned short lgA[128 * TBK];
  __shared__ __align__(16) unsigned short lgB[BN * TBK];
  const int tid = threadIdx.x;
  const int lane = tid & 63;
  const int w = tid >> 6;
  const int wr = w >> 1, wc = w & 1;
  const int lr = lane & 15, kg = lane >> 4;

  f32x4 acc[4][NF];
  #pragma unroll
  for (int m = 0; m < 4; m++)
    #pragma unroll
    for (int n = 0; n < NF; n++)
      #pragma unroll
      for (int q = 0; q < 4; q++) acc[m][n][q] = 0.f;

  for (int k0 = 0; k0 < K; k0 += TBK) {
    __syncthreads();
    #pragma unroll
    for (int it = 0; it < AIT; ++it) {
      const int off = it * 4096 + tid * 16;
      const int kp = off / PA, row = (off % PA) >> 6, colb = off & 63;
      const char* ga = (const char*)A + (size_t)(row0 + row) * (lda * 2) + (k0 + kp * 32) * 2 + colb;
      __builtin_amdgcn_global_load_lds((const __attribute__((address_space(1))) unsigned int*)ga,
                                       (__attribute__((address_space(3))) unsigned int*)((char*)lgA + off), 16, 0, 0);
    }
    #pragma unroll
    for (int it = 0; it < BIT; ++it) {
      const int off = it * 4096 + tid * 16;
      const int kp = off / PB, row = (off % PB) >> 6, colb = off & 63;
      const char* gb = (const char*)Bt + (size_t)(col0 + row) * (ldb * 2) + (k0 + kp * 32) * 2 + colb;
      __builtin_amdgcn_global_load_lds((const __attribute__((address_space(1))) unsigned int*)gb,
                                       (__attribute__((address_space(3))) unsigned int*)((char*)lgB + off), 16, 0, 0);
    }
    __syncthreads();
    #pragma unroll
    for (int kk = 0; kk < TBK; kk += 32) {
      short8 af[4], bfr[NF];
      #pragma unroll
      for (int m = 0; m < 4; m++)
        af[m] = *(const short8*)&lgA[(kk >> 5) * (128 * 32) + (wr * 64 + m * 16 + lr) * 32 + kg * 8];
      #pragma unroll
      for (int n = 0; n < NF; n++)
        bfr[n] = *(const short8*)&lgB[(kk >> 5) * (BN * 32) + (wc * (BN / 2) + n * 16 + lr) * 32 + kg * 8];
      #pragma unroll
      for (int m = 0; m < 4; m++)
        #pragma unroll
        for (int n = 0; n < NF; n++)
          acc[m][n] = __builtin_amdgcn_mfma_f32_16x16x32_bf16(af[m], bfr[n], acc[m][n], 0, 0, 0);
    }
  }

  #pragma unroll
  for (int m = 0; m < 4; m++) {
    #pragma unroll
    for (int n = 0; n < NF; n++) {
      const int gc = col0 + wc * (BN / 2) + n * 16 + lr;
      if (gc >= Nvalid) continue;
      #pragma unroll
      for (int j = 0; j < 4; j++) {
        const int gr = row0 + wr * 64 + m * 16 + kg * 4 + j;
        if (gr >= M) continue;
        float v = acc[m][n][j];
        if (bias) v += bias[gc];
        if (SELFC) {
          v += selfacc[(size_t)gr * 768 + z * 64 + gc] * scl[(size_t)gr * 12 + z]
             + simw[(size_t)gr * 12 + z] * bv2[z * 64 + gc];
        }
        const size_t idx = (size_t)gr * ldc + gc;
        if (OUT_BF16) {
          unsigned short* C = (unsigned short*)Cv + (size_t)zsC * z;
          C[idx] = f2bf(v);
        } else {
          float* C = (float*)Cv + (size_t)zsC * z;
          C[idx] = v;
        }
      }
    }
  }
}

// ----------------- merged: attn_self (768 blks) + T-GEMM (2304) ------------
// T row-major [r][h*768 + D] (R11 layout — see header note (3)).

__global__ __launch_bounds__(256, 2)
void tattn_kernel(const unsigned short* __restrict__ qkv,
                  const unsigned short* __restrict__ Wk_bf,
                  unsigned short* __restrict__ Tbuf,
                  float* __restrict__ selfacc,
                  float* __restrict__ mstat,
                  float* __restrict__ sstat)
{
  __shared__ __align__(16) char smem[70656];
  const int tid = threadIdx.x;
  const int lane = tid & 63;
  const int w = tid >> 6;
  const int lr = lane & 15, kg = lane >> 4;

  if (blockIdx.x >= 768) {
    // ---------------- T-GEMM body ----------------
    const int bid = blockIdx.x - 768;
    const int xb = bid % 32, yb = (bid / 32) % 6, z = bid / 192;
    const int row0 = xb * 128, col0 = yb * 128;
    const int wr = w >> 1, wc = w & 1;
    const unsigned short* A  = qkv + 64 * z;          // lda 2304
    const unsigned short* Bt = Wk_bf + 64 * z;        // ldb 768
    unsigned short* lgA = (unsigned short*)smem;               // 128x64
    unsigned short* lgB = (unsigned short*)(smem + 16384);     // 128x64

    f32x4 acc[4][4];
    #pragma unroll
    for (int m = 0; m < 4; m++)
      #pragma unroll
      for (int n = 0; n < 4; n++)
        #pragma unroll
        for (int q = 0; q < 4; q++) acc[m][n][q] = 0.f;

    #pragma unroll
    for (int it = 0; it < 4; ++it) {
      const int off = it * 4096 + tid * 16;
      const int kp = off / 8192, row = (off % 8192) >> 6, colb = off & 63;
      const char* ga = (const char*)A + (size_t)(row0 + row) * 4608 + (kp * 32) * 2 + colb;
      __builtin_amdgcn_global_load_lds((const __attribute__((address_space(1))) unsigned int*)ga,
                                       (__attribute__((address_space(3))) unsigned int*)((char*)lgA + off), 16, 0, 0);
      const char* gb = (const char*)Bt + (size_t)(col0 + row) * 1536 + (kp * 32) * 2 + colb;
      __builtin_amdgcn_global_load_lds((const __attribute__((address_space(1))) unsigned int*)gb,
                                       (__attribute__((address_space(3))) unsigned int*)((char*)lgB + off), 16, 0, 0);
    }
    __syncthreads();
    #pragma unroll
    for (int kk = 0; kk < 64; kk += 32) {
      short8 af[4], bfr[4];
      #pragma unroll
      for (int m = 0; m < 4; m++)
        af[m] = *(const short8*)&lgA[(kk >> 5) * 4096 + (wr * 64 + m * 16 + lr) * 32 + kg * 8];
      #pragma unroll
      for (int n = 0; n < 4; n++)
        bfr[n] = *(const short8*)&lgB[(kk >> 5) * 4096 + (wc * 64 + n * 16 + lr) * 32 + kg * 8];
      #pragma unroll
      for (int m = 0; m < 4; m++)
        #pragma unroll
        for (int n = 0; n < 4; n++)
          acc[m][n] = __builtin_amdgcn_mfma_f32_16x16x32_bf16(af[m], bfr[n], acc[m][n], 0, 0, 0);
    }
    #pragma unroll
    for (int m = 0; m < 4; m++)
      #pragma unroll
      for (int n = 0; n < 4; n++) {
        const int gc = col0 + wc * 64 + n * 16 + lr;
        #pragma unroll
        for (int j = 0; j < 4; j++) {
          const int gr = row0 + wr * 64 + m * 16 + kg * 4 + j;
          Tbuf[(size_t)gr * 9216 + z * 768 + gc] = f2bf(acc[m][n][j]);
        }
      }
    return;
  }

  // ---------------- attn_self body ----------------
  const int bh = blockIdx.x >> 2;
  const int qq = blockIdx.x & 3;
  const int b = bh / 12;
  const int h = bh % 12;
  const size_t rowbase = (size_t)b * 256;
  const int rows0 = qq * 64 + w * 16;            // this wave's 16 q-rows

  unsigned short* Ks = (unsigned short*)smem;             // [256][72]
  unsigned short* VT = (unsigned short*)(smem + 36864);   // [64][264]  VT[d][k]=V[k][d]
  unsigned short* aL = (unsigned short*)(smem + (size_t)w * 4352); // [16][136]/wave, aliases Ks

  for (int it = 0; it < 8; ++it) {
    const int idx = tid * 8 + it * 2048;
    const int row = idx >> 6, d = idx & 63;
    *(short8*)&Ks[row * 72 + d] =
        *(const short8*)&qkv[(rowbase + row) * 2304 + 768 + h * 64 + d];
  }
  #pragma unroll
  for (int it = 0; it < 16; ++it) {
    const int kk = w * 64 + it * 4 + kg;
    const int d0 = lr * 4;
    u16x4 v4 = *(const u16x4*)&qkv[(rowbase + kk) * 2304 + 1536 + h * 64 + d0];
    VT[(d0+0) * 264 + kk] = v4.x;
    VT[(d0+1) * 264 + kk] = v4.y;
    VT[(d0+2) * 264 + kk] = v4.z;
    VT[(d0+3) * 264 + kk] = v4.w;
  }
  __syncthreads();

  f32x4 acc[16];
  #pragma unroll
  for (int n = 0; n < 16; n++)
    #pragma unroll
    for (int q = 0; q < 4; q++) acc[n][q] = 0.f;

  #pragma unroll
  for (int ks = 0; ks < 64; ks += 32) {           // QK^T, K=64; Q from global
    short8 af = *(const short8*)&qkv[(rowbase + rows0 + lr) * 2304 + h * 64 + ks + kg * 8];
    #pragma unroll
    for (int n = 0; n < 16; n++) {
      short8 bfr = *(const short8*)&Ks[(n * 16 + lr) * 72 + ks + kg * 8];
      acc[n] = __builtin_amdgcn_mfma_f32_16x16x32_bf16(af, bfr, acc[n], 0, 0, 0);
    }
  }

  #pragma unroll
  for (int j = 0; j < 4; j++) {
    float vmx = -1e30f;
    #pragma unroll
    for (int n = 0; n < 16; n++) { float s = acc[n][j] * 0.125f; acc[n][j] = s; vmx = fmaxf(vmx, s); }
    #pragma unroll
    for (int s = 1; s < 16; s <<= 1) vmx = fmaxf(vmx, __shfl_xor(vmx, s));
    float sum = 0.f;
    #pragma unroll
    for (int n = 0; n < 16; n++) { float e = __expf(acc[n][j] - vmx); acc[n][j] = e; sum += e; }
    #pragma unroll
    for (int s = 1; s < 16; s <<= 1) sum += __shfl_xor(sum, s);
    if (lr == 0) {
      const int row = rows0 + kg * 4 + j;
      mstat[(rowbase + row) * 12 + h] = vmx;
      sstat[(rowbase + row) * 12 + h] = sum;
    }
  }

  __syncthreads();   // all waves done reading Ks before aL overwrites it

  f32x4 acc2[4];
  #pragma unroll
  for (int m = 0; m < 4; m++)
    #pragma unroll
    for (int q = 0; q < 4; q++) acc2[m][q] = 0.f;

  #pragma unroll
  for (int hl = 0; hl < 2; ++hl) {   // PV in two 128-col halves
    #pragma unroll
    for (int j = 0; j < 4; j++) {
      const int rw = kg * 4 + j;
      #pragma unroll
      for (int n2 = 0; n2 < 8; n2++)
        aL[rw * 136 + n2 * 16 + lr] = f2bf(acc[hl * 8 + n2][j]);   // unnormalized
    }
    #pragma unroll
    for (int ks2 = 0; ks2 < 4; ++ks2) {   // out^T = VT * a^T
      short8 pf = *(const short8*)&aL[lr * 136 + ks2 * 32 + kg * 8];
      #pragma unroll
      for (int mm = 0; mm < 4; mm++) {
        short8 vf = *(const short8*)&VT[(mm * 16 + lr) * 264 + hl * 128 + ks2 * 32 + kg * 8];
        acc2[mm] = __builtin_amdgcn_mfma_f32_16x16x32_bf16(vf, pf, acc2[mm], 0, 0, 0);
      }
    }
  }

  #pragma unroll
  for (int mm = 0; mm < 4; mm++)      // D rows = dh, D cols = q-row (lr)
    #pragma unroll
    for (int j = 0; j < 4; j++) {
      const int dh = mm * 16 + kg * 4 + j;
      const int rn = rows0 + lr;
      selfacc[(rowbase + rn) * 768 + h * 64 + dh] = acc2[mm][j];   // f32 unnorm
    }
}

// --------------------- fused sim logits + renorm + s_v (MFMA) --------------
// One block per (b,n) = r, 8 waves, 512 threads.  (R11 structure.)

__global__ __launch_bounds__(512, 4)
void fused_sim_kernel(const float* __restrict__ se, const unsigned short* __restrict__ T,
                      const unsigned short* __restrict__ qkv, const float* __restrict__ bk,
                      const float* __restrict__ mstat, const float* __restrict__ sstat,
                      unsigned short* __restrict__ s_v,
                      float* __restrict__ sclA, float* __restrict__ simwA)
{
  const int r = blockIdx.x;                    // b*256+n
  __shared__ __align__(16) unsigned int SE_T32[768 * 9];   // 27648 B
  __shared__ __align__(16) unsigned int SErm[16][388];     // 24832 B (776-elem rows)
  __shared__ __align__(16) float Lp[8][64][4];             // 8192 B
  __shared__ float qb[16];
  const int tid = threadIdx.x;
  const int w = tid >> 6, lane = tid & 63;
  const int lr = lane & 15, kg = lane >> 4;

  // ---- coalesced stage: wave w owns se rows m = {2w, 2w+1} ----
  const float* se_r = se + (size_t)r * 12288;
  unsigned short va[2][12];
  #pragma unroll
  for (int c = 0; c < 3; ++c) {
    float4 fa = *(const float4*)&se_r[(2 * w) * 768 + c * 256 + lane * 4];
    float4 fb = *(const float4*)&se_r[(2 * w + 1) * 768 + c * 256 + lane * 4];
    va[0][c*4+0] = f2bf(fa.x); va[0][c*4+1] = f2bf(fa.y); va[0][c*4+2] = f2bf(fa.z); va[0][c*4+3] = f2bf(fa.w);
    va[1][c*4+0] = f2bf(fb.x); va[1][c*4+1] = f2bf(fb.y); va[1][c*4+2] = f2bf(fb.z); va[1][c*4+3] = f2bf(fb.w);
  }
  #pragma unroll
  for (int c = 0; c < 3; ++c) {
    #pragma unroll
    for (int j = 0; j < 4; ++j) {        // SE_T: m-pair packed, swizzled dword col
      const int d = c * 256 + lane * 4 + j;
      SE_T32[d * 9 + (w ^ ((d >> 5) & 7))] =
          (unsigned int)va[0][c*4+j] | ((unsigned int)va[1][c*4+j] << 16);
    }
    #pragma unroll
    for (int rr = 0; rr < 2; ++rr) {     // SErm: row-major k-pairs, b64 writes
      uint2 pk;
      pk.x = (unsigned int)va[rr][c*4+0] | ((unsigned int)va[rr][c*4+1] << 16);
      pk.y = (unsigned int)va[rr][c*4+2] | ((unsigned int)va[rr][c*4+3] << 16);
      *(uint2*)&SErm[2 * w + rr][c * 128 + lane * 2] = pk;
    }
  }
  // qb[h] = q_h . bk_h  (waves 0..5, 2 heads each)
  if (w < 6) {
    #pragma unroll
    for (int i = 0; i < 2; ++i) {
      const int hh = w * 2 + i;
      float p = bf2f(qkv[(size_t)r * 2304 + hh * 64 + lane]) * bk[hh * 64 + lane];
      #pragma unroll
      for (int sft = 32; sft; sft >>= 1) p += __shfl_xor(p, sft);
      if (lane == 0) qb[hh] = p;
    }
  }
  if (tid < 4) qb[12 + tid] = 0.f;

  // T B-frags (row-major [h][D]); lanes 12-15 clamp to h=11 (results discarded)
  const int hsel = (lr < 12) ? lr : 11;
  short8 bfr[3];
  #pragma unroll
  for (int s = 0; s < 3; ++s)
    bfr[s] = *(const short8*)&T[(size_t)r * 9216 + hsel * 768 + w * 96 + s * 32 + kg * 8];

  __syncthreads();

  // ---- L-GEMM partial: K in [w*96, w*96+96) ----
  f32x4 accL = {0.f, 0.f, 0.f, 0.f};
  #pragma unroll
  for (int s = 0; s < 3; ++s) {
    const int kb = w * 96 + s * 32 + kg * 8;
    short8 af = *(const short8*)&SErm[lr][kb >> 1];
    accL = __builtin_amdgcn_mfma_f32_16x16x32_bf16(af, bfr[s], accL, 0, 0, 0);
  }
  *(f32x4*)&Lp[w][lane][0] = accL;
  __syncthreads();

  // ---- softmax + joint renorm (redundant per wave; m=kg*4+j, h=lr) ----
  float vals[4] = {0.f, 0.f, 0.f, 0.f};
  #pragma unroll
  for (int ww = 0; ww < 8; ++ww) {
    f32x4 p = *(const f32x4*)&Lp[ww][lane][0];
    vals[0] += p[0]; vals[1] += p[1]; vals[2] += p[2]; vals[3] += p[3];
  }
  #pragma unroll
  for (int j = 0; j < 4; ++j) vals[j] = vals[j] * 0.125f + qb[lr];
  float mx = fmaxf(fmaxf(vals[0], vals[1]), fmaxf(vals[2], vals[3]));
  mx = fmaxf(mx, __shfl_xor(mx, 16));
  mx = fmaxf(mx, __shfl_xor(mx, 32));
  const int hidx = r * 12 + (lr < 12 ? lr : 11);
  const float msf = mstat[hidx];
  const float ssf = sstat[hidx];
  const float mj = fmaxf(mx, msf);
  float ea[4];
  #pragma unroll
  for (int j = 0; j < 4; ++j) ea[j] = __expf(vals[j] - mj);
  float ssum = ea[0] + ea[1] + ea[2] + ea[3];
  ssum += __shfl_xor(ssum, 16);
  ssum += __shfl_xor(ssum, 32);
  const float alpha = __expf(msf - mj);
  const float invZ = 1.0f / (ssf * alpha + ssum);
  float a[4];
  #pragma unroll
  for (int j = 0; j < 4; ++j) a[j] = ea[j] * invZ;
  if (w == 0 && kg == 0 && lr < 12) {
    sclA[(size_t)r * 12 + lr]  = alpha * invZ;
    simwA[(size_t)r * 12 + lr] = ssum * invZ;
  }

  // ---- a^T A-frag: lane (h=lr, kg) needs a[m=kg*8+e][h], zeros for kg>=2 ----
  short8 af8;
  #pragma unroll
  for (int e = 0; e < 8; ++e) {
    const int src = lr + ((kg & 1) * 2 + (e >> 2)) * 16;
    const float v = __shfl(a[e & 3], src);
    af8[e] = (kg < 2) ? (short)f2bf(v) : (short)0;
  }

  // ---- s_v GEMM: 6 d-tiles per wave, one mfma each ----
  #pragma unroll
  for (int i = 0; i < 6; ++i) {
    const int ntile = w + i * 8;
    const int row = ntile * 16 + lr;
    const int sw = (row >> 5) & 7;
    union { unsigned int u[4]; short8 s8; } bu;
    #pragma unroll
    for (int j = 0; j < 4; ++j)
      bu.u[j] = SE_T32[row * 9 + (((kg & 1) * 4 + j) ^ sw)];
    f32x4 cacc = {0.f, 0.f, 0.f, 0.f};
    cacc = __builtin_amdgcn_mfma_f32_16x16x32_bf16(af8, bu.s8, cacc, 0, 0, 0);
    if (kg < 3) {
      #pragma unroll
      for (int j = 0; j < 4; ++j) {
        const int h = kg * 4 + j;
        s_v[(size_t)r * 9216 + h * 768 + ntile * 16 + lr] = f2bf(cacc[j]);
      }
    }
  }
}

// ------------------------------- launcher ----------------------------------

extern "C" void kernel_launch(void* const* d_in, const int* in_sizes, int n_in,
                              void* d_out, int out_size, void* d_ws, size_t ws_size,
                              hipStream_t stream) {
  const float* x  = (const float*)d_in[0];
  const float* se = (const float*)d_in[1];
  const float* Wq = (const float*)d_in[2];
  const float* bq = (const float*)d_in[3];
  const float* Wk = (const float*)d_in[4];
  const float* bk = (const float*)d_in[5];
  const float* Wv = (const float*)d_in[6];
  const float* bv = (const float*)d_in[7];
  const float* Wp = (const float*)d_in[8];
  const float* bp = (const float*)d_in[9];
  float* out = (float*)d_out;
  char* ws = (char*)d_ws;

  // workspace layout (256B-aligned), total ~120.4 MB
  unsigned short* x_bf    = (unsigned short*)(ws);                 // 4096x768   bf16
  unsigned short* Wqkv_t  = (unsigned short*)(ws + 6291456);       // 2304x768   bf16  Wq^T|Wk^T|Wv^T rows
  unsigned short* Wp_t    = (unsigned short*)(ws + 9830400);       // 768x768    bf16
  unsigned short* Wk_bf   = (unsigned short*)(ws + 11010048);      // 768x768    bf16 (untransposed)
  float*          bqkv    = (float*)(ws + 12189696);               // 2304       f32
  unsigned short* qkv     = (unsigned short*)(ws + 12198912);      // 4096x2304  bf16  q|k|v
  unsigned short* Tbuf    = (unsigned short*)(ws + 31073280);      // 4096x12x768 bf16  T, then s_v
  float*          selfacc = (float*)(ws + 106570752);              // 4096x768   f32  unnorm out_self
  float*          mstat   = (float*)(ws + 119153664);              // 4096x12    f32
  float*          sstat   = (float*)(ws + 119350272);              // 4096x12    f32
  float*          sclA    = (float*)(ws + 119546880);              // 4096x12    f32
  float*          simwA   = (float*)(ws + 119743488);              // 4096x12    f32
  unsigned short* att     = (unsigned short*)(ws + 119940096);     // 4096x768   bf16

  prep_all<<<5376, 256, 0, stream>>>(x, x_bf, Wq, Wk, Wv, Wp, Wqkv_t, Wp_t,
                                     Wk_bf, bq, bk, bv, bqkv);

  // qkv = x @ [Wq|Wk|Wv] + bias: 256x128 tile, 512 threads, 288 blocks
  gemm_qkv<<<288, 512, 0, stream>>>(x_bf, Wqkv_t, qkv, bqkv);

  // merged: attn_self (768 blocks) + T-GEMM (2304 blocks)
  tattn_kernel<<<3072, 256, 0, stream>>>(qkv, Wk_bf, Tbuf, selfacc, mstat, sstat);

  fused_sim_kernel<<<4096, 512, 0, stream>>>(se, Tbuf, qkv, bk, mstat, sstat,
                                             Tbuf /* s_v overwrites T in-place per r */,
                                             sclA, simwA);

  // att = selfacc*scl + s_v_h @ Wv_h + simw*bv_h   (ZY: z = s/32, 384 blocks)
  gemm_bt<true, true, 64, 32, true, true><<<384, 256, 0, stream>>>(
      Tbuf, 9216, 768, Wqkv_t + 1536 * 768, 768, 64 * 768, att, 768, 64,
      4096, 64, 768, 384, nullptr, selfacc, sclA, simwA, bv);
  // out = att @ Wp + bp  (f32 out), yb = s/32 (ZY=false), 384 blocks, swizzled
  gemm_bt<false, false, 64, 32, true, false><<<384, 256, 0, stream>>>(
      att, 768, 0, Wp_t, 768, 0, out, 768, 0, 4096, 768, 768, 384,
      bp, nullptr, nullptr, nullptr, nullptr);
}